// Round 1
// baseline (161.933 us; speedup 1.0000x reference)
//
#include <hip/hip_runtime.h>

// DirDist_P2P: fused jittered-query construction + exact 5-NN against two
// 2048-point clouds + inverse-distance UDF/grad + weighted scalar loss.
//
// Layout: 8 sub-threads per query, each scans a 256-point chunk of each cloud
// maintaining a sorted top-5 of packed (f32 d2 | idx) u64s; merged via 3
// shfl_xor rounds (merge-path rank formula). Clouds staged in LDS with +1
// dword chunk padding so the 8 per-sub addresses hit 8 distinct banks.

#define NPTS   2048
#define UPR    10
#define KNN    5
#define QTOT   (NPTS * UPR + NPTS)   // 22528
#define SUBS   8
#define CHUNK  (NPTS / SUBS)          // 256 points per sub-thread
#define CH_STRIDE (CHUNK * 3 + 1)     // 769 dwords: breaks bank aliasing across subs
#define QPB    32                     // queries per block (256 threads / 8 subs)
#define BLOCK  256
#define NBLOCKS (QTOT / QPB)          // 704

static __device__ __forceinline__ unsigned long long umin64(unsigned long long a, unsigned long long b) {
    return a < b ? a : b;
}
static __device__ __forceinline__ unsigned long long umax64(unsigned long long a, unsigned long long b) {
    return a < b ? b : a;
}
static __device__ __forceinline__ unsigned long long shfl_xor64(unsigned long long v, int mask) {
    unsigned lo = (unsigned)v;
    unsigned hi = (unsigned)(v >> 32);
    lo = __shfl_xor((int)lo, mask, 64);
    hi = __shfl_xor((int)hi, mask, 64);
    return ((unsigned long long)hi << 32) | (unsigned long long)lo;
}

struct UdfResult { float udf, gx, gy, gz; };

// Scan one cloud (in LDS, chunk-padded layout), produce UDF + grad for this
// lane's query. All 8 lanes of a query group return identical results.
static __device__ __forceinline__ void process_cloud(const float* lds, float qx, float qy, float qz,
                                                     int sub, UdfResult& r) {
    unsigned long long b0 = ~0ULL, b1 = ~0ULL, b2 = ~0ULL, b3 = ~0ULL, b4 = ~0ULL;
    const float* base = lds + sub * CH_STRIDE;
    const int gbase = sub * CHUNK;

#pragma unroll 4
    for (int j = 0; j < CHUNK; ++j) {
        float x = base[j * 3 + 0];
        float y = base[j * 3 + 1];
        float z = base[j * 3 + 2];
        float dx = qx - x, dy = qy - y, dz = qz - z;
        float d2 = dx * dx + dy * dy + dz * dz;
        unsigned long long p =
            ((unsigned long long)__float_as_uint(d2) << 32) | (unsigned)(gbase + j);
        // branchless sorted-insert into ascending 5-list
        bool c0 = p < b0, c1 = p < b1, c2 = p < b2, c3 = p < b3, c4 = p < b4;
        b4 = c4 ? (c3 ? b3 : p) : b4;
        b3 = c3 ? (c2 ? b2 : p) : b3;
        b2 = c2 ? (c1 ? b1 : p) : b2;
        b1 = c1 ? (c0 ? b0 : p) : b1;
        b0 = c0 ? p : b0;
    }

    // merge the 8 sub-lists across lanes (xor 1, 2, 4). Both partners compute
    // the identical smallest-5 union (merge-path rank formula; lists sorted).
#pragma unroll
    for (int mask = 1; mask <= 4; mask <<= 1) {
        unsigned long long c0 = shfl_xor64(b0, mask);
        unsigned long long c1 = shfl_xor64(b1, mask);
        unsigned long long c2 = shfl_xor64(b2, mask);
        unsigned long long c3 = shfl_xor64(b3, mask);
        unsigned long long c4 = shfl_xor64(b4, mask);
        unsigned long long n0 = umin64(b0, c0);
        unsigned long long n1 = umin64(umin64(b1, c1), umax64(b0, c0));
        unsigned long long n2 = umin64(umin64(b2, c2),
                               umin64(umax64(b1, c0), umax64(b0, c1)));
        unsigned long long n3 = umin64(umin64(b3, c3),
                               umin64(umax64(b2, c0),
                               umin64(umax64(b1, c1), umax64(b0, c2))));
        unsigned long long n4 = umin64(umin64(b4, c4),
                               umin64(umax64(b3, c0),
                               umin64(umax64(b2, c1),
                               umin64(umax64(b1, c2), umax64(b0, c3)))));
        b0 = n0; b1 = n1; b2 = n2; b3 = n3; b4 = n4;
    }

    // inverse-distance weights -> udf grad
    unsigned long long bs[KNN] = { b0, b1, b2, b3, b4 };
    float wsum = 0.f, gx = 0.f, gy = 0.f, gz = 0.f;
#pragma unroll
    for (int i = 0; i < KNN; ++i) {
        float d2 = __uint_as_float((unsigned)(bs[i] >> 32));
        unsigned idx = (unsigned)bs[i];
        const float* pp = lds + (idx >> 8) * CH_STRIDE + (idx & 255u) * 3;
        float inv = 1.0f / (d2 + 1e-8f);
        wsum += inv;
        gx += (qx - pp[0]) * inv;
        gy += (qy - pp[1]) * inv;
        gz += (qz - pp[2]) * inv;
    }
    float rs = 1.0f / wsum;
    gx *= rs; gy *= rs; gz *= rs;
    float ex = gx + 1e-10f, ey = gy + 1e-10f, ez = gz + 1e-10f;
    r.udf = sqrtf(ex * ex + ey * ey + ez * ez);
    r.gx = gx; r.gy = gy; r.gz = gz;
}

__global__ __launch_bounds__(BLOCK) void knn_loss_kernel(const float* __restrict__ src,
                                                         const float* __restrict__ tgt,
                                                         const float* __restrict__ noise,
                                                         float* __restrict__ partial) {
    __shared__ float lt[SUBS * CH_STRIDE];   // tgt cloud, chunk-padded
    __shared__ float ls[SUBS * CH_STRIDE];   // src cloud, chunk-padded
    __shared__ float redw[BLOCK / 64];

    const int tid = threadIdx.x;

    // stage both clouds into LDS
    for (int p = tid; p < NPTS; p += BLOCK) {
        int c = p >> 8, l = p & 255;
        int db = c * CH_STRIDE + l * 3;
        lt[db + 0] = tgt[3 * p + 0];
        lt[db + 1] = tgt[3 * p + 1];
        lt[db + 2] = tgt[3 * p + 2];
        ls[db + 0] = src[3 * p + 0];
        ls[db + 1] = src[3 * p + 1];
        ls[db + 2] = src[3 * p + 2];
    }

    // build this lane's query point (8 lanes per query, redundant)
    const int q = blockIdx.x * QPB + (tid >> 3);
    const int sub = tid & 7;
    float qx, qy, qz;
    if (q < NPTS * UPR) {
        int m = q / UPR;
        qx = tgt[3 * m + 0] + 0.05f * noise[3 * q + 0];
        qy = tgt[3 * m + 1] + 0.05f * noise[3 * q + 1];
        qz = tgt[3 * m + 2] + 0.05f * noise[3 * q + 2];
    } else {
        int i = q - NPTS * UPR;
        qx = src[3 * i + 0];
        qy = src[3 * i + 1];
        qz = src[3 * i + 2];
    }

    __syncthreads();

    UdfResult rt, rsr;
    process_cloud(lt, qx, qy, qz, sub, rt);
    process_cloud(ls, qx, qy, qz, sub, rsr);

    float ue  = fabsf(rt.udf - rsr.udf);
    float uge = fabsf(rsr.gx - rt.gx) + fabsf(rsr.gy - rt.gy) + fabsf(rsr.gz - rt.gz);
    float qw  = expf(-ue * 3.0f) * expf(-uge * 3.0f);
    float term = (ue + uge) * qw;
    float contrib = (sub == 0) ? term : 0.f;

    // wave butterfly sum
#pragma unroll
    for (int m = 1; m < 64; m <<= 1) contrib += __shfl_xor(contrib, m, 64);
    if ((tid & 63) == 0) redw[tid >> 6] = contrib;
    __syncthreads();
    if (tid == 0) partial[blockIdx.x] = redw[0] + redw[1] + redw[2] + redw[3];
}

__global__ __launch_bounds__(BLOCK) void final_reduce_kernel(const float* __restrict__ partial,
                                                             float* __restrict__ out) {
    double s = 0.0;
    for (int i = threadIdx.x; i < NBLOCKS; i += BLOCK) s += (double)partial[i];
#pragma unroll
    for (int m = 1; m < 64; m <<= 1) s += __shfl_xor(s, m, 64);
    __shared__ double red[BLOCK / 64];
    if ((threadIdx.x & 63) == 0) red[threadIdx.x >> 6] = s;
    __syncthreads();
    if (threadIdx.x == 0)
        out[0] = (float)((red[0] + red[1] + red[2] + red[3]) / (double)QTOT);
}

extern "C" void kernel_launch(void* const* d_in, const int* in_sizes, int n_in,
                              void* d_out, int out_size, void* d_ws, size_t ws_size,
                              hipStream_t stream) {
    const float* src   = (const float*)d_in[0];
    const float* tgt   = (const float*)d_in[1];
    const float* noise = (const float*)d_in[2];
    float* out = (float*)d_out;
    float* partial = (float*)d_ws;   // NBLOCKS floats

    knn_loss_kernel<<<NBLOCKS, BLOCK, 0, stream>>>(src, tgt, noise, partial);
    final_reduce_kernel<<<1, BLOCK, 0, stream>>>(partial, out);
}

// Round 2
// 105.510 us; speedup vs baseline: 1.5348x; 1.5348x over previous
//
#include <hip/hip_runtime.h>

// DirDist_P2P: fused jittered-query construction + exact 5-NN against two
// 2048-point clouds + inverse-distance UDF/grad + weighted scalar loss.
//
// R2: 32-bit packed keys ((d2&0xFFFFF800)|idx) + min/max sorted-insert
// (b_i = min(b_i, max(b_{i-1}, p)) — 9 VALU, no compares/cndmask), exact d2
// recomputed from idx in epilogue. Chunk stride 772 dwords (16B aligned) so
// 4 points = 3x ds_read_b128, banks 4*sub apart (conflict-free).

#define NPTS   2048
#define UPR    10
#define KNN    5
#define QTOT   (NPTS * UPR + NPTS)   // 22528
#define SUBS   8
#define CHUNK  (NPTS / SUBS)          // 256 points per sub-thread
#define CH_STRIDE 772                 // dwords; 772*4=3088 B (16B aligned), bank offset 4*sub
#define QPB    32                     // queries per block (256 threads / 8 subs)
#define BLOCK  256
#define NBLOCKS (QTOT / QPB)          // 704

static __device__ __forceinline__ unsigned umin32(unsigned a, unsigned b) { return a < b ? a : b; }
static __device__ __forceinline__ unsigned umax32(unsigned a, unsigned b) { return a < b ? b : a; }

struct UdfResult { float udf, gx, gy, gz; };

// p0..p3 insert helper: b_i = min(b_i, max(b_{i-1}, p)), top-down (old values).
#define INSERT5(p)                         \
    do {                                   \
        unsigned _p = (p);                 \
        b4 = umin32(b4, umax32(b3, _p));   \
        b3 = umin32(b3, umax32(b2, _p));   \
        b2 = umin32(b2, umax32(b1, _p));   \
        b1 = umin32(b1, umax32(b0, _p));   \
        b0 = umin32(b0, _p);               \
    } while (0)

// Scan one cloud (in LDS, chunk-padded layout), produce UDF + grad for this
// lane's query. All 8 lanes of a query group return identical results.
static __device__ __forceinline__ void process_cloud(const float* lds, float qx, float qy, float qz,
                                                     int sub, UdfResult& r) {
    unsigned b0 = 0xFFFFFFFFu, b1 = 0xFFFFFFFFu, b2 = 0xFFFFFFFFu,
             b3 = 0xFFFFFFFFu, b4 = 0xFFFFFFFFu;
    const float4* base4 = reinterpret_cast<const float4*>(lds + sub * CH_STRIDE);
    unsigned idx = (unsigned)(sub * CHUNK);

#pragma unroll 4
    for (int g = 0; g < CHUNK / 4; ++g) {
        float4 A = base4[3 * g + 0];   // p0.xyz p1.x
        float4 B = base4[3 * g + 1];   // p1.yz  p2.xy
        float4 C = base4[3 * g + 2];   // p2.z   p3.xyz

        float dx, dy, dz, d2;
        unsigned p;

        dx = qx - A.x; dy = qy - A.y; dz = qz - A.z;
        d2 = dx * dx + dy * dy + dz * dz;
        p = (__float_as_uint(d2) & 0xFFFFF800u) | idx;
        INSERT5(p); ++idx;

        dx = qx - A.w; dy = qy - B.x; dz = qz - B.y;
        d2 = dx * dx + dy * dy + dz * dz;
        p = (__float_as_uint(d2) & 0xFFFFF800u) | idx;
        INSERT5(p); ++idx;

        dx = qx - B.z; dy = qy - B.w; dz = qz - C.x;
        d2 = dx * dx + dy * dy + dz * dz;
        p = (__float_as_uint(d2) & 0xFFFFF800u) | idx;
        INSERT5(p); ++idx;

        dx = qx - C.y; dy = qy - C.z; dz = qz - C.w;
        d2 = dx * dx + dy * dy + dz * dz;
        p = (__float_as_uint(d2) & 0xFFFFF800u) | idx;
        INSERT5(p); ++idx;
    }

    // merge the 8 sub-lists across lanes (xor 1, 2, 4). Both partners compute
    // the identical smallest-5 union (merge-path rank formula; lists sorted).
#pragma unroll
    for (int mask = 1; mask <= 4; mask <<= 1) {
        unsigned c0 = (unsigned)__shfl_xor((int)b0, mask, 64);
        unsigned c1 = (unsigned)__shfl_xor((int)b1, mask, 64);
        unsigned c2 = (unsigned)__shfl_xor((int)b2, mask, 64);
        unsigned c3 = (unsigned)__shfl_xor((int)b3, mask, 64);
        unsigned c4 = (unsigned)__shfl_xor((int)b4, mask, 64);
        unsigned n0 = umin32(b0, c0);
        unsigned n1 = umin32(umin32(b1, c1), umax32(b0, c0));
        unsigned n2 = umin32(umin32(b2, c2),
                      umin32(umax32(b1, c0), umax32(b0, c1)));
        unsigned n3 = umin32(umin32(b3, c3),
                      umin32(umax32(b2, c0),
                      umin32(umax32(b1, c1), umax32(b0, c2))));
        unsigned n4 = umin32(umin32(b4, c4),
                      umin32(umax32(b3, c0),
                      umin32(umax32(b2, c1),
                      umin32(umax32(b1, c2), umax32(b0, c3)))));
        b0 = n0; b1 = n1; b2 = n2; b3 = n3; b4 = n4;
    }

    // inverse-distance weights -> udf grad. Exact d2 recomputed from idx.
    unsigned bs[KNN] = { b0, b1, b2, b3, b4 };
    float wsum = 0.f, gx = 0.f, gy = 0.f, gz = 0.f;
#pragma unroll
    for (int i = 0; i < KNN; ++i) {
        unsigned id = bs[i] & 0x7FFu;
        const float* pp = lds + (id >> 8) * CH_STRIDE + (id & 255u) * 3;
        float dx = qx - pp[0], dy = qy - pp[1], dz = qz - pp[2];
        float d2 = dx * dx + dy * dy + dz * dz;
        float inv = 1.0f / (d2 + 1e-8f);
        wsum += inv;
        gx += dx * inv;
        gy += dy * inv;
        gz += dz * inv;
    }
    float rs = 1.0f / wsum;
    gx *= rs; gy *= rs; gz *= rs;
    float ex = gx + 1e-10f, ey = gy + 1e-10f, ez = gz + 1e-10f;
    r.udf = sqrtf(ex * ex + ey * ey + ez * ez);
    r.gx = gx; r.gy = gy; r.gz = gz;
}

__global__ __launch_bounds__(BLOCK) void knn_loss_kernel(const float* __restrict__ src,
                                                         const float* __restrict__ tgt,
                                                         const float* __restrict__ noise,
                                                         float* __restrict__ partial) {
    __shared__ float lt[SUBS * CH_STRIDE];   // tgt cloud, chunk-padded
    __shared__ float ls[SUBS * CH_STRIDE];   // src cloud, chunk-padded
    __shared__ float redw[BLOCK / 64];

    const int tid = threadIdx.x;

    // stage both clouds into LDS
    for (int p = tid; p < NPTS; p += BLOCK) {
        int c = p >> 8, l = p & 255;
        int db = c * CH_STRIDE + l * 3;
        lt[db + 0] = tgt[3 * p + 0];
        lt[db + 1] = tgt[3 * p + 1];
        lt[db + 2] = tgt[3 * p + 2];
        ls[db + 0] = src[3 * p + 0];
        ls[db + 1] = src[3 * p + 1];
        ls[db + 2] = src[3 * p + 2];
    }

    // build this lane's query point (8 lanes per query, redundant)
    const int q = blockIdx.x * QPB + (tid >> 3);
    const int sub = tid & 7;
    float qx, qy, qz;
    if (q < NPTS * UPR) {
        int m = q / UPR;
        qx = tgt[3 * m + 0] + 0.05f * noise[3 * q + 0];
        qy = tgt[3 * m + 1] + 0.05f * noise[3 * q + 1];
        qz = tgt[3 * m + 2] + 0.05f * noise[3 * q + 2];
    } else {
        int i = q - NPTS * UPR;
        qx = src[3 * i + 0];
        qy = src[3 * i + 1];
        qz = src[3 * i + 2];
    }

    __syncthreads();

    UdfResult rt, rsr;
    process_cloud(lt, qx, qy, qz, sub, rt);
    process_cloud(ls, qx, qy, qz, sub, rsr);

    float ue  = fabsf(rt.udf - rsr.udf);
    float uge = fabsf(rsr.gx - rt.gx) + fabsf(rsr.gy - rt.gy) + fabsf(rsr.gz - rt.gz);
    float qw  = expf(-ue * 3.0f) * expf(-uge * 3.0f);
    float term = (ue + uge) * qw;
    float contrib = (sub == 0) ? term : 0.f;

    // wave butterfly sum
#pragma unroll
    for (int m = 1; m < 64; m <<= 1) contrib += __shfl_xor(contrib, m, 64);
    if ((tid & 63) == 0) redw[tid >> 6] = contrib;
    __syncthreads();
    if (tid == 0) partial[blockIdx.x] = redw[0] + redw[1] + redw[2] + redw[3];
}

__global__ __launch_bounds__(BLOCK) void final_reduce_kernel(const float* __restrict__ partial,
                                                             float* __restrict__ out) {
    double s = 0.0;
    for (int i = threadIdx.x; i < NBLOCKS; i += BLOCK) s += (double)partial[i];
#pragma unroll
    for (int m = 1; m < 64; m <<= 1) s += __shfl_xor(s, m, 64);
    __shared__ double red[BLOCK / 64];
    if ((threadIdx.x & 63) == 0) red[threadIdx.x >> 6] = s;
    __syncthreads();
    if (threadIdx.x == 0)
        out[0] = (float)((red[0] + red[1] + red[2] + red[3]) / (double)QTOT);
}

extern "C" void kernel_launch(void* const* d_in, const int* in_sizes, int n_in,
                              void* d_out, int out_size, void* d_ws, size_t ws_size,
                              hipStream_t stream) {
    const float* src   = (const float*)d_in[0];
    const float* tgt   = (const float*)d_in[1];
    const float* noise = (const float*)d_in[2];
    float* out = (float*)d_out;
    float* partial = (float*)d_ws;   // NBLOCKS floats

    knn_loss_kernel<<<NBLOCKS, BLOCK, 0, stream>>>(src, tgt, noise, partial);
    final_reduce_kernel<<<1, BLOCK, 0, stream>>>(partial, out);
}